// Round 1
// baseline (362.153 us; speedup 1.0000x reference)
//
#include <hip/hip_runtime.h>

#define NN 16384
#define DIM 64
#define NPART 128

// ---- pos/neg: rowwise sums of relu(g) and relu(-g). One block per row. ----
__global__ __launch_bounds__(256) void rowsum_kernel(const float* __restrict__ g,
                                                     float* __restrict__ pos,
                                                     float* __restrict__ neg) {
    int row = blockIdx.x;
    const float4* grow = reinterpret_cast<const float4*>(g + (size_t)row * NN);
    float p = 0.f, n = 0.f;
    #pragma unroll 4
    for (int i = threadIdx.x; i < NN / 4; i += 256) {
        float4 v = grow[i];
        p += fmaxf(v.x, 0.f) + fmaxf(v.y, 0.f) + fmaxf(v.z, 0.f) + fmaxf(v.w, 0.f);
        n += fmaxf(-v.x, 0.f) + fmaxf(-v.y, 0.f) + fmaxf(-v.z, 0.f) + fmaxf(-v.w, 0.f);
    }
    #pragma unroll
    for (int o = 32; o > 0; o >>= 1) {
        p += __shfl_down(p, o, 64);
        n += __shfl_down(n, o, 64);
    }
    __shared__ float sp[4], sn[4];
    int wid = threadIdx.x >> 6;
    if ((threadIdx.x & 63) == 0) { sp[wid] = p; sn[wid] = n; }
    __syncthreads();
    if (threadIdx.x == 0) {
        pos[row] = sp[0] + sp[1] + sp[2] + sp[3];
        neg[row] = sn[0] + sn[1] + sn[2] + sn[3];
    }
}

// ---- a3 = W3 @ relu(w4), b3 = W3 @ relu(-w4) ----
__global__ void pre_kernel(const float* __restrict__ W3, const float* __restrict__ w4,
                           float* __restrict__ a3, float* __restrict__ b3) {
    int d = threadIdx.x;
    float a = 0.f, b = 0.f;
    #pragma unroll
    for (int k = 0; k < DIM; ++k) {
        float w = W3[d * DIM + k];
        a += w * fmaxf(w4[k], 0.f);
        b += w * fmaxf(-w4[k], 0.f);
    }
    a3[d] = a;
    b3[d] = b;
}

// ---- u1 = relu(base), base[i,d] = x[i]*w1[d] + pos[i]*a3[d] + neg[i]*b3[d] ----
__global__ __launch_bounds__(256) void init_kernel(const int* __restrict__ s_mask,
                                                   const float* __restrict__ w1,
                                                   const float* __restrict__ pos,
                                                   const float* __restrict__ neg,
                                                   const float* __restrict__ a3,
                                                   const float* __restrict__ b3,
                                                   float* __restrict__ u) {
    int idx = blockIdx.x * 256 + threadIdx.x;
    int i = idx >> 6, d = idx & 63;
    float x = (float)s_mask[i];
    float b = x * w1[d] + pos[i] * a3[d] + neg[i] * b3[d];
    u[idx] = fmaxf(b, 0.f);
}

// ---- stage-1 node-sum reduction: partials[b][d] = sum over block's rows ----
__global__ __launch_bounds__(256) void reduce1_kernel(const float* __restrict__ u,
                                                      float* __restrict__ partials) {
    int d = threadIdx.x & 63;
    int sub = threadIdx.x >> 6;              // 0..3
    const int rows_per_block = NN / NPART;   // 128
    int row0 = blockIdx.x * rows_per_block;
    float acc = 0.f;
    for (int r = sub; r < rows_per_block; r += 4)
        acc += u[(size_t)(row0 + r) * DIM + d];
    __shared__ float s[4][DIM];
    s[sub][d] = acc;
    __syncthreads();
    if (sub == 0)
        partials[blockIdx.x * DIM + d] = s[0][d] + s[1][d] + s[2][d] + s[3][d];
}

// ---- stage-2: summ[d] = sum_b partials[b][d] ----
__global__ void reduce2_kernel(const float* __restrict__ partials, float* __restrict__ summ) {
    int d = threadIdx.x;
    float acc = 0.f;
    for (int b = 0; b < NPART; ++b) acc += partials[b * DIM + d];
    summ[d] = acc;
}

// ---- u[i] = relu(base[i] + (summ - u[i]) @ W2^T), base recomputed on the fly ----
__global__ __launch_bounds__(256) void update_kernel(const int* __restrict__ s_mask,
                                                     const float* __restrict__ w1,
                                                     const float* __restrict__ pos,
                                                     const float* __restrict__ neg,
                                                     const float* __restrict__ a3,
                                                     const float* __restrict__ b3,
                                                     float* __restrict__ u,
                                                     const float* __restrict__ summ,
                                                     const float* __restrict__ W2) {
    __shared__ float w2t[DIM * DIM];  // w2t[k*64+d] = W2[d*64+k] (transposed: lanes read consecutive)
    __shared__ float us[4][DIM];
    __shared__ float ss[DIM];
    int tid = threadIdx.x;
    for (int idx = tid; idx < DIM * DIM; idx += 256) {
        int d = idx >> 6, k = idx & 63;
        w2t[k * DIM + d] = W2[idx];
    }
    if (tid < DIM) ss[tid] = summ[tid];
    int r = tid >> 6, d = tid & 63;
    int row = blockIdx.x * 4 + r;
    us[r][d] = u[(size_t)row * DIM + d];
    __syncthreads();
    float acc = 0.f;
    #pragma unroll
    for (int k = 0; k < DIM; ++k)
        acc += w2t[k * DIM + d] * (ss[k] - us[r][k]);  // w2t: conflict-free, us/ss: broadcast
    float x = (float)s_mask[row];
    float b = x * w1[d] + pos[row] * a3[d] + neg[row] * b3[d];
    u[(size_t)row * DIM + d] = fmaxf(b + acc, 0.f);
}

// ---- q(v): h6 = summ@W6^T, h7 = u[v]@W7^T, out = relu(cat) @ w5 ----
__global__ void final_kernel(const float* __restrict__ summ, const float* __restrict__ u,
                             const int* __restrict__ vptr,
                             const float* __restrict__ W6, const float* __restrict__ W7,
                             const float* __restrict__ w5, float* __restrict__ out) {
    int tid = threadIdx.x;  // 128 threads
    int v = *vptr;
    float h = 0.f;
    if (tid < 64) {
        #pragma unroll
        for (int k = 0; k < DIM; ++k) h += W6[tid * DIM + k] * summ[k];
    } else {
        int d = tid - 64;
        const float* uv = u + (size_t)v * DIM;
        #pragma unroll
        for (int k = 0; k < DIM; ++k) h += W7[d * DIM + k] * uv[k];
    }
    h = fmaxf(h, 0.f) * w5[tid];
    __shared__ float s[128];
    s[tid] = h;
    __syncthreads();
    for (int stride = 64; stride > 0; stride >>= 1) {
        if (tid < stride) s[tid] += s[tid + stride];
        __syncthreads();
    }
    if (tid == 0) out[0] = s[0];
}

extern "C" void kernel_launch(void* const* d_in, const int* in_sizes, int n_in,
                              void* d_out, int out_size, void* d_ws, size_t ws_size,
                              hipStream_t stream) {
    const float* graph  = (const float*)d_in[0];
    const int*   s_mask = (const int*)d_in[1];
    const int*   vptr   = (const int*)d_in[2];
    const float* w1     = (const float*)d_in[3];
    const float* W2     = (const float*)d_in[4];
    const float* W3     = (const float*)d_in[5];
    const float* w4     = (const float*)d_in[6];
    const float* w5     = (const float*)d_in[7];
    const float* W6     = (const float*)d_in[8];
    const float* W7     = (const float*)d_in[9];
    float* out = (float*)d_out;

    float* ws       = (float*)d_ws;
    float* pos      = ws;                          // NN
    float* neg      = pos + NN;                    // NN
    float* u        = neg + NN;                    // NN*DIM
    float* partials = u + (size_t)NN * DIM;        // NPART*DIM
    float* a3       = partials + NPART * DIM;      // DIM
    float* b3       = a3 + DIM;                    // DIM
    float* summ     = b3 + DIM;                    // DIM
    // total ~ (2*NN + NN*64 + 128*64 + 192) * 4 B  ~= 4.3 MB of ws

    rowsum_kernel<<<NN, 256, 0, stream>>>(graph, pos, neg);
    pre_kernel<<<1, DIM, 0, stream>>>(W3, w4, a3, b3);
    init_kernel<<<NN * DIM / 256, 256, 0, stream>>>(s_mask, w1, pos, neg, a3, b3, u);
    for (int t = 0; t < 3; ++t) {  // iterations 2..4 (iter 1 == relu(base), done by init)
        reduce1_kernel<<<NPART, 256, 0, stream>>>(u, partials);
        reduce2_kernel<<<1, DIM, 0, stream>>>(partials, summ);
        update_kernel<<<NN / 4, 256, 0, stream>>>(s_mask, w1, pos, neg, a3, b3, u, summ, W2);
    }
    reduce1_kernel<<<NPART, 256, 0, stream>>>(u, partials);
    reduce2_kernel<<<1, DIM, 0, stream>>>(partials, summ);
    final_kernel<<<1, 128, 0, stream>>>(summ, u, vptr, W6, W7, w5, out);
}